// Round 1
// baseline (1136.725 us; speedup 1.0000x reference)
//
#include <hip/hip_runtime.h>

typedef unsigned long long u64;

#define NNODES 12288
#define WORDS 192   // 12288 / 64 bits per row

// ---------------- adjacency build: bitmask M[s][d], MT[d][s] ----------------
__global__ void build_mask_kernel(const int* __restrict__ ei, u64* __restrict__ M,
                                  u64* __restrict__ MT, int E) {
    int e = blockIdx.x * blockDim.x + threadIdx.x;
    if (e >= E) return;
    int s = ei[e];
    int d = ei[E + e];
    atomicOr(&M[(size_t)s * WORDS + (d >> 6)], 1ull << (d & 63));
    atomicOr(&MT[(size_t)d * WORDS + (s >> 6)], 1ull << (s & 63));
}

// deg[i] = popcount(M row i) + popcount(MT row i); dinv = 1/(deg + 1e-8)
__global__ void dinv_kernel(const u64* __restrict__ M, const u64* __restrict__ MT,
                            float* __restrict__ dinv) {
    int row = blockIdx.x * 4 + (threadIdx.x >> 6);   // wave per row, 4 rows/block
    int lane = threadIdx.x & 63;
    int cnt = 0;
    for (int w = lane; w < WORDS; w += 64) {
        cnt += __popcll(M[(size_t)row * WORDS + w]);
        cnt += __popcll(MT[(size_t)row * WORDS + w]);
    }
    #pragma unroll
    for (int off = 32; off > 0; off >>= 1) cnt += __shfl_down(cnt, off, 64);
    if (lane == 0) dinv[row] = 1.0f / ((float)cnt + 1e-8f);
}

// ---------------- agg = x + dinv * (M @ x + MT @ x) ----------------
// one block per row; thread t owns column t; per-wave-uniform bit decode
__global__ __launch_bounds__(256) void spmm_agg_kernel(
        const float* __restrict__ x, const u64* __restrict__ M, const u64* __restrict__ MT,
        const float* __restrict__ dinv, float* __restrict__ out) {
    const int H = 256;
    int row = blockIdx.x;
    int t = threadIdx.x;
    const u64* rM = M + (size_t)row * WORDS;
    const u64* rMT = MT + (size_t)row * WORDS;
    float acc = 0.0f;
    for (int w = 0; w < WORDS; ++w) {
        u64 bits = rM[w];
        while (bits) {
            int j = (w << 6) + __builtin_ctzll(bits);
            bits &= bits - 1;
            acc += x[(size_t)j * H + t];
        }
    }
    for (int w = 0; w < WORDS; ++w) {
        u64 bits = rMT[w];
        while (bits) {
            int j = (w << 6) + __builtin_ctzll(bits);
            bits &= bits - 1;
            acc += x[(size_t)j * H + t];
        }
    }
    size_t o = (size_t)row * H + t;
    out[o] = x[o] + dinv[row] * acc;
}

// ---------------- Y = act(X @ W^T + b) ----------------
// X [N,K] row-major, W [M,K] row-major (torch Linear layout), Y [N,M].
// 64x64 tile / block of 256, 4x4 per thread, BK=32, LDS transposed stride 68
// (16B-aligned b128 reads in compute phase; 4-way conflict only on stores).
template<bool RELU>
__global__ __launch_bounds__(256) void gemm_kernel(
        const float* __restrict__ X, const float* __restrict__ W,
        const float* __restrict__ bias, float* __restrict__ Y,
        int K, int Mcols) {
    const int BK = 32, LDP = 68;
    __shared__ float Xs[BK * LDP];
    __shared__ float Ws[BK * LDP];
    int tid = threadIdx.x;
    int row0 = blockIdx.x * 64;
    int col0 = blockIdx.y * 64;
    int tx = tid & 15, ty = tid >> 4;
    float acc[4][4] = {};
    for (int k0 = 0; k0 < K; k0 += BK) {
        #pragma unroll
        for (int i = 0; i < 2; ++i) {
            int f = tid + i * 256;          // 512 float4 slots: r in [0,64), kk in {0,4,..,28}
            int r = f >> 3;
            int kk = (f & 7) << 2;
            float4 vx = *(const float4*)&X[(size_t)(row0 + r) * K + k0 + kk];
            float4 vw = *(const float4*)&W[(size_t)(col0 + r) * K + k0 + kk];
            Xs[(kk + 0) * LDP + r] = vx.x;
            Xs[(kk + 1) * LDP + r] = vx.y;
            Xs[(kk + 2) * LDP + r] = vx.z;
            Xs[(kk + 3) * LDP + r] = vx.w;
            Ws[(kk + 0) * LDP + r] = vw.x;
            Ws[(kk + 1) * LDP + r] = vw.y;
            Ws[(kk + 2) * LDP + r] = vw.z;
            Ws[(kk + 3) * LDP + r] = vw.w;
        }
        __syncthreads();
        #pragma unroll
        for (int k = 0; k < BK; ++k) {
            float4 a = *(const float4*)&Xs[k * LDP + (ty << 2)];
            float4 b = *(const float4*)&Ws[k * LDP + (tx << 2)];
            float av[4] = {a.x, a.y, a.z, a.w};
            float bv[4] = {b.x, b.y, b.z, b.w};
            #pragma unroll
            for (int i2 = 0; i2 < 4; ++i2)
                #pragma unroll
                for (int j2 = 0; j2 < 4; ++j2)
                    acc[i2][j2] += av[i2] * bv[j2];
        }
        __syncthreads();
    }
    float4 b4 = *(const float4*)&bias[col0 + (tx << 2)];
    float bb[4] = {b4.x, b4.y, b4.z, b4.w};
    #pragma unroll
    for (int i2 = 0; i2 < 4; ++i2) {
        int row = row0 + (ty << 2) + i2;
        float4 v;
        float* vp = (float*)&v;
        #pragma unroll
        for (int j2 = 0; j2 < 4; ++j2) {
            float t = acc[i2][j2] + bb[j2];
            if (RELU) t = fmaxf(t, 0.0f);
            vp[j2] = t;
        }
        *(float4*)&Y[(size_t)row * Mcols + col0 + (tx << 2)] = v;
    }
}

// tiny head: Y[N,M] = X[N,K] @ W[M,K]^T + b, K<=64, M small (8)
__global__ void gemm_small_kernel(const float* __restrict__ X, const float* __restrict__ W,
                                  const float* __restrict__ bias, float* __restrict__ Y,
                                  int N, int K, int M) {
    int idx = blockIdx.x * blockDim.x + threadIdx.x;
    if (idx >= N * M) return;
    int r = idx / M, m = idx % M;
    float s = bias[m];
    const float* xr = X + (size_t)r * K;
    const float* wr = W + (size_t)m * K;
    for (int k = 0; k < K; ++k) s += xr[k] * wr[k];
    Y[idx] = s;
}

// gf[t] = mean over rows of ne[:,t]; gf pre-zeroed, partial sums via atomicAdd
__global__ void col_mean_kernel(const float* __restrict__ ne, float* __restrict__ gf, int N, int D) {
    int t = threadIdx.x;   // 0..127
    float s = 0.0f;
    for (int r = blockIdx.x; r < N; r += gridDim.x) s += ne[(size_t)r * D + t];
    atomicAdd(&gf[t], s * (1.0f / (float)N));
}

extern "C" void kernel_launch(void* const* d_in, const int* in_sizes, int n_in,
                              void* d_out, int out_size, void* d_ws, size_t ws_size,
                              hipStream_t stream) {
    const int N = NNODES, H = 256;
    const float* nf     = (const float*)d_in[0];
    const int*   ei     = (const int*)d_in[1];
    const float* enc_w1 = (const float*)d_in[2];
    const float* enc_b1 = (const float*)d_in[3];
    const float* enc_w2 = (const float*)d_in[4];
    const float* enc_b2 = (const float*)d_in[5];
    const float* gin_w  = (const float*)d_in[6];
    const float* gin_b  = (const float*)d_in[7];
    const float* gl_w   = (const float*)d_in[8];
    const float* gl_b   = (const float*)d_in[9];
    const float* gout_w = (const float*)d_in[10];
    const float* gout_b = (const float*)d_in[11];
    const float* proj_w = (const float*)d_in[12];
    const float* proj_b = (const float*)d_in[13];
    const float* hc_w1  = (const float*)d_in[14];
    const float* hc_b1  = (const float*)d_in[15];
    const float* hc_w2  = (const float*)d_in[16];
    const float* hc_b2  = (const float*)d_in[17];
    const int E = in_sizes[1] >> 1;

    // workspace carve (all offsets 16B aligned)
    char* ws = (char*)d_ws;
    u64* M  = (u64*)ws;                                   // 18,874,368 B
    u64* MT = M + (size_t)N * WORDS;                      // 18,874,368 B
    float* dinv = (float*)(MT + (size_t)N * WORDS);       // 49,152 B
    float* bufA = dinv + N;
    float* bufB = bufA + (size_t)N * H;
    float* bufC = bufB + (size_t)N * H;

    float* ne     = (float*)d_out;                        // [N,128]
    float* logits = ne + (size_t)N * 128;                 // [N,8]
    float* gf     = logits + (size_t)N * 8;               // [128]

    hipMemsetAsync(M, 0, 2 * (size_t)N * WORDS * sizeof(u64), stream);
    hipMemsetAsync(gf, 0, 128 * sizeof(float), stream);

    build_mask_kernel<<<(E + 255) / 256, 256, 0, stream>>>(ei, M, MT, E);
    dinv_kernel<<<N / 4, 256, 0, stream>>>(M, MT, dinv);

    dim3 g256(N / 64, 4);   // 256 output cols
    // encoder: t1 = relu(nf @ enc_w1^T + b1); h = t1 @ enc_w2^T + b2
    gemm_kernel<true ><<<g256, 256, 0, stream>>>(nf,   enc_w1, enc_b1, bufA, 256, 256);
    gemm_kernel<false><<<g256, 256, 0, stream>>>(bufA, enc_w2, enc_b2, bufB, 256, 256);
    // x = relu(h @ gin_w^T + gin_b)
    gemm_kernel<true ><<<g256, 256, 0, stream>>>(bufB, gin_w, gin_b, bufA, 256, 256);

    float* cur = bufA;
    float* nxt = bufB;
    for (int i = 0; i < 3; ++i) {
        spmm_agg_kernel<<<N, 256, 0, stream>>>(cur, M, MT, dinv, bufC);
        gemm_kernel<true><<<g256, 256, 0, stream>>>(bufC, gl_w + (size_t)i * H * H,
                                                    gl_b + (size_t)i * H, nxt, 256, 256);
        float* tmp = cur; cur = nxt; nxt = tmp;
    }
    // x = x @ gout_w^T + gout_b  (no relu)
    gemm_kernel<false><<<g256, 256, 0, stream>>>(cur, gout_w, gout_b, nxt, 256, 256);
    // ne = relu(x @ proj_w^T + proj_b)   [N,128] straight into d_out
    gemm_kernel<true ><<<dim3(N / 64, 2), 256, 0, stream>>>(nxt, proj_w, proj_b, ne, 256, 128);
    // t = relu(ne @ hc_w1^T + hc_b1)     [N,64]
    gemm_kernel<true ><<<dim3(N / 64, 1), 256, 0, stream>>>(ne, hc_w1, hc_b1, bufC, 128, 64);
    // logits = t @ hc_w2^T + hc_b2       [N,8]
    gemm_small_kernel<<<(N * 8 + 255) / 256, 256, 0, stream>>>(bufC, hc_w2, hc_b2, logits, N, 64, 8);
    // gf = mean(ne, axis=0)
    col_mean_kernel<<<192, 128, 0, stream>>>(ne, gf, N, 128);
}

// Round 2
// 617.009 us; speedup vs baseline: 1.8423x; 1.8423x over previous
//
#include <hip/hip_runtime.h>

typedef unsigned long long u64;

#define NNODES 12288
#define WORDS 192   // 12288 / 64 bits per row
#define ELLW 256    // max neighbors per row (avg 64, Poisson tail safe)

// ---------------- adjacency build: bitmask M[s][d], MT[d][s] ----------------
__global__ void build_mask_kernel(const int* __restrict__ ei, u64* __restrict__ M,
                                  u64* __restrict__ MT, int E) {
    int e = blockIdx.x * blockDim.x + threadIdx.x;
    if (e >= E) return;
    int s = ei[e];
    int d = ei[E + e];
    atomicOr(&M[(size_t)s * WORDS + (d >> 6)], 1ull << (d & 63));
    atomicOr(&MT[(size_t)d * WORDS + (s >> 6)], 1ull << (s & 63));
}

// ---------------- bitmask -> ELL neighbor list + cnt + dinv ----------------
// one wave per row; M entries then MT entries (dup pairs appear twice = weight 2)
__global__ __launch_bounds__(256) void ell_fill_kernel(
        const u64* __restrict__ M, const u64* __restrict__ MT,
        int* __restrict__ ell, int* __restrict__ cnt, float* __restrict__ dinv) {
    int row = blockIdx.x * 4 + (threadIdx.x >> 6);
    int lane = threadIdx.x & 63;
    const u64* rM  = M  + (size_t)row * WORDS;
    const u64* rMT = MT + (size_t)row * WORDS;
    u64 wm[3], wt[3];
    int pm = 0, pt = 0;
    #pragma unroll
    for (int k = 0; k < 3; ++k) {
        wm[k] = rM[lane + 64 * k];  pm += __popcll(wm[k]);
        wt[k] = rMT[lane + 64 * k]; pt += __popcll(wt[k]);
    }
    // wave inclusive scans
    int inclM = pm, inclT = pt;
    #pragma unroll
    for (int off = 1; off < 64; off <<= 1) {
        int ym = __shfl_up(inclM, off, 64);
        int yt = __shfl_up(inclT, off, 64);
        if (lane >= off) { inclM += ym; inclT += yt; }
    }
    int exclM = inclM - pm;
    int exclT = inclT - pt;
    int totM = __shfl(inclM, 63, 64);
    int totT = __shfl(inclT, 63, 64);
    int* out = ell + (size_t)row * ELLW;
    int pos = exclM;
    #pragma unroll
    for (int k = 0; k < 3; ++k) {
        u64 bits = wm[k];
        int base = (lane + 64 * k) << 6;
        while (bits) { out[pos++] = base + __builtin_ctzll(bits); bits &= bits - 1; }
    }
    pos = totM + exclT;
    #pragma unroll
    for (int k = 0; k < 3; ++k) {
        u64 bits = wt[k];
        int base = (lane + 64 * k) << 6;
        while (bits) { out[pos++] = base + __builtin_ctzll(bits); bits &= bits - 1; }
    }
    if (lane == 0) {
        int n = totM + totT;
        cnt[row] = n;
        dinv[row] = 1.0f / ((float)n + 1e-8f);
    }
}

// ---------------- agg = x + dinv * sum_{j in ell[row]} x[j] ----------------
// block = 1 row; 4 waves split neighbors; lane owns float4 of the 256 cols;
// unroll-4 -> 4 outstanding 1KB gathers per wave
__global__ __launch_bounds__(256) void spmm_ell_kernel(
        const float* __restrict__ x, const int* __restrict__ ell,
        const int* __restrict__ cnt, const float* __restrict__ dinv,
        float* __restrict__ out) {
    int row = blockIdx.x;
    int t = threadIdx.x;
    int w = t >> 6, lane = t & 63;
    const float4* x4 = (const float4*)x;
    const int* ridx = ell + (size_t)row * ELLW;
    int n = cnt[row];
    float4 acc = make_float4(0.f, 0.f, 0.f, 0.f);
    int i = w;
    for (; i + 12 < n; i += 16) {
        int j0 = ridx[i];
        int j1 = ridx[i + 4];
        int j2 = ridx[i + 8];
        int j3 = ridx[i + 12];
        float4 a0 = x4[(size_t)j0 * 64 + lane];
        float4 a1 = x4[(size_t)j1 * 64 + lane];
        float4 a2 = x4[(size_t)j2 * 64 + lane];
        float4 a3 = x4[(size_t)j3 * 64 + lane];
        acc.x += (a0.x + a1.x) + (a2.x + a3.x);
        acc.y += (a0.y + a1.y) + (a2.y + a3.y);
        acc.z += (a0.z + a1.z) + (a2.z + a3.z);
        acc.w += (a0.w + a1.w) + (a2.w + a3.w);
    }
    for (; i < n; i += 4) {
        float4 a = x4[(size_t)ridx[i] * 64 + lane];
        acc.x += a.x; acc.y += a.y; acc.z += a.z; acc.w += a.w;
    }
    __shared__ float4 part[4][64];
    part[w][lane] = acc;
    __syncthreads();
    const float* pf = (const float*)part;
    float s = (pf[t] + pf[256 + t]) + (pf[512 + t] + pf[768 + t]);
    size_t o = (size_t)row * 256 + t;
    out[o] = x[o] + dinv[row] * s;
}

// ---------------- Y = act(X @ W^T + b) ----------------
template<bool RELU>
__global__ __launch_bounds__(256) void gemm_kernel(
        const float* __restrict__ X, const float* __restrict__ W,
        const float* __restrict__ bias, float* __restrict__ Y,
        int K, int Mcols) {
    const int BK = 32, LDP = 68;
    __shared__ float Xs[BK * LDP];
    __shared__ float Ws[BK * LDP];
    int tid = threadIdx.x;
    int row0 = blockIdx.x * 64;
    int col0 = blockIdx.y * 64;
    int tx = tid & 15, ty = tid >> 4;
    float acc[4][4] = {};
    for (int k0 = 0; k0 < K; k0 += BK) {
        #pragma unroll
        for (int i = 0; i < 2; ++i) {
            int f = tid + i * 256;
            int r = f >> 3;
            int kk = (f & 7) << 2;
            float4 vx = *(const float4*)&X[(size_t)(row0 + r) * K + k0 + kk];
            float4 vw = *(const float4*)&W[(size_t)(col0 + r) * K + k0 + kk];
            Xs[(kk + 0) * LDP + r] = vx.x;
            Xs[(kk + 1) * LDP + r] = vx.y;
            Xs[(kk + 2) * LDP + r] = vx.z;
            Xs[(kk + 3) * LDP + r] = vx.w;
            Ws[(kk + 0) * LDP + r] = vw.x;
            Ws[(kk + 1) * LDP + r] = vw.y;
            Ws[(kk + 2) * LDP + r] = vw.z;
            Ws[(kk + 3) * LDP + r] = vw.w;
        }
        __syncthreads();
        #pragma unroll
        for (int k = 0; k < BK; ++k) {
            float4 a = *(const float4*)&Xs[k * LDP + (ty << 2)];
            float4 b = *(const float4*)&Ws[k * LDP + (tx << 2)];
            float av[4] = {a.x, a.y, a.z, a.w};
            float bv[4] = {b.x, b.y, b.z, b.w};
            #pragma unroll
            for (int i2 = 0; i2 < 4; ++i2)
                #pragma unroll
                for (int j2 = 0; j2 < 4; ++j2)
                    acc[i2][j2] += av[i2] * bv[j2];
        }
        __syncthreads();
    }
    float4 b4 = *(const float4*)&bias[col0 + (tx << 2)];
    float bb[4] = {b4.x, b4.y, b4.z, b4.w};
    #pragma unroll
    for (int i2 = 0; i2 < 4; ++i2) {
        int row = row0 + (ty << 2) + i2;
        float4 v;
        float* vp = (float*)&v;
        #pragma unroll
        for (int j2 = 0; j2 < 4; ++j2) {
            float tv = acc[i2][j2] + bb[j2];
            if (RELU) tv = fmaxf(tv, 0.0f);
            vp[j2] = tv;
        }
        *(float4*)&Y[(size_t)row * Mcols + col0 + (tx << 2)] = v;
    }
}

// tiny head: Y[N,M] = X[N,K] @ W[M,K]^T + b, K<=64, M small (8)
__global__ void gemm_small_kernel(const float* __restrict__ X, const float* __restrict__ W,
                                  const float* __restrict__ bias, float* __restrict__ Y,
                                  int N, int K, int M) {
    int idx = blockIdx.x * blockDim.x + threadIdx.x;
    if (idx >= N * M) return;
    int r = idx / M, m = idx % M;
    float s = bias[m];
    const float* xr = X + (size_t)r * K;
    const float* wr = W + (size_t)m * K;
    for (int k = 0; k < K; ++k) s += xr[k] * wr[k];
    Y[idx] = s;
}

__global__ void col_mean_kernel(const float* __restrict__ ne, float* __restrict__ gf, int N, int D) {
    int t = threadIdx.x;   // 0..127
    float s = 0.0f;
    for (int r = blockIdx.x; r < N; r += gridDim.x) s += ne[(size_t)r * D + t];
    atomicAdd(&gf[t], s * (1.0f / (float)N));
}

extern "C" void kernel_launch(void* const* d_in, const int* in_sizes, int n_in,
                              void* d_out, int out_size, void* d_ws, size_t ws_size,
                              hipStream_t stream) {
    const int N = NNODES, H = 256;
    const float* nf     = (const float*)d_in[0];
    const int*   ei     = (const int*)d_in[1];
    const float* enc_w1 = (const float*)d_in[2];
    const float* enc_b1 = (const float*)d_in[3];
    const float* enc_w2 = (const float*)d_in[4];
    const float* enc_b2 = (const float*)d_in[5];
    const float* gin_w  = (const float*)d_in[6];
    const float* gin_b  = (const float*)d_in[7];
    const float* gl_w   = (const float*)d_in[8];
    const float* gl_b   = (const float*)d_in[9];
    const float* gout_w = (const float*)d_in[10];
    const float* gout_b = (const float*)d_in[11];
    const float* proj_w = (const float*)d_in[12];
    const float* proj_b = (const float*)d_in[13];
    const float* hc_w1  = (const float*)d_in[14];
    const float* hc_b1  = (const float*)d_in[15];
    const float* hc_w2  = (const float*)d_in[16];
    const float* hc_b2  = (const float*)d_in[17];
    const int E = in_sizes[1] >> 1;

    // workspace carve:
    // [0, 37.75MB): masks M,MT -- dead after ell_fill; ALIASED by bufA/B/C after
    // [37.75MB, ...): ell (12.58MB), cnt, dinv  -- live for whole launch
    char* ws = (char*)d_ws;
    u64* M  = (u64*)ws;
    u64* MT = M + (size_t)N * WORDS;
    int* ell = (int*)(MT + (size_t)N * WORDS);
    int* cntb = ell + (size_t)N * ELLW;
    float* dinv = (float*)(cntb + N);
    float* bufA = (float*)ws;              // aliases M/MT (3*12.58MB == 2*18.87MB)
    float* bufB = bufA + (size_t)N * H;
    float* bufC = bufB + (size_t)N * H;

    float* ne     = (float*)d_out;                        // [N,128]
    float* logits = ne + (size_t)N * 128;                 // [N,8]
    float* gf     = logits + (size_t)N * 8;               // [128]

    hipMemsetAsync(M, 0, 2 * (size_t)N * WORDS * sizeof(u64), stream);
    hipMemsetAsync(gf, 0, 128 * sizeof(float), stream);

    build_mask_kernel<<<(E + 255) / 256, 256, 0, stream>>>(ei, M, MT, E);
    ell_fill_kernel<<<N / 4, 256, 0, stream>>>(M, MT, ell, cntb, dinv);
    // masks dead from here; bufA/B/C may clobber them

    dim3 g256(N / 64, 4);
    gemm_kernel<true ><<<g256, 256, 0, stream>>>(nf,   enc_w1, enc_b1, bufA, 256, 256);
    gemm_kernel<false><<<g256, 256, 0, stream>>>(bufA, enc_w2, enc_b2, bufB, 256, 256);
    gemm_kernel<true ><<<g256, 256, 0, stream>>>(bufB, gin_w, gin_b, bufA, 256, 256);

    float* cur = bufA;
    float* nxt = bufB;
    for (int i = 0; i < 3; ++i) {
        spmm_ell_kernel<<<N, 256, 0, stream>>>(cur, ell, cntb, dinv, bufC);
        gemm_kernel<true><<<g256, 256, 0, stream>>>(bufC, gl_w + (size_t)i * H * H,
                                                    gl_b + (size_t)i * H, nxt, 256, 256);
        float* tmp = cur; cur = nxt; nxt = tmp;
    }
    gemm_kernel<false><<<g256, 256, 0, stream>>>(cur, gout_w, gout_b, nxt, 256, 256);
    gemm_kernel<true ><<<dim3(N / 64, 2), 256, 0, stream>>>(nxt, proj_w, proj_b, ne, 256, 128);
    gemm_kernel<true ><<<dim3(N / 64, 1), 256, 0, stream>>>(ne, hc_w1, hc_b1, bufC, 128, 64);
    gemm_small_kernel<<<(N * 8 + 255) / 256, 256, 0, stream>>>(bufC, hc_w2, hc_b2, logits, N, 64, 8);
    col_mean_kernel<<<192, 128, 0, stream>>>(ne, gf, N, 128);
}